// Round 1
// baseline (717.276 us; speedup 1.0000x reference)
//
#include <hip/hip_runtime.h>

// Problem constants (B=4, N=512, M=32768, D=1024, H=16, hd=64, K=32)
#define BTOK   2048
#define DDIM   1024
#define MKEYS  32768
#define NHEAD  16
#define HDIM   64
#define KSEL   32

// workspace layout (float offsets)
#define WS_QFULL 0
#define WS_CTX   (BTOK * DDIM)                 // 2097152
#define WS_S     (WS_CTX + BTOK * DDIM)        // 4194304
#define WS_S2    (WS_S + MKEYS)                // 4227072
#define WS_QM    (WS_S2 + MKEYS)               // 4259840
#define WS_KP    (WS_QM + BTOK)                // 4261888
#define WS_VP    (WS_KP + 64 * DDIM)           // 4327424
#define WS_IDX   (WS_VP + 64 * DDIM)           // 4392960 (64 ints)
#define WS_RAW   WS_QFULL                      // out_raw aliases q_full (dead after attention)

// d_out layout (float offsets)
#define OUT_AVG  (BTOK * DDIM)                 // 2097152
#define OUT_IDX  (OUT_AVG + BTOK * KSEL)       // 2162688

// ---------------------------------------------------------------------------
// 1) per-row sum and norm of memory_keys -> s[m] = sum/norm, s2[m] = -s[m]
//    one wave per row, float4 loads, shuffle reduce.
__global__ __launch_bounds__(256) void reduce_keys(const float* __restrict__ mk,
                                                   float* __restrict__ s,
                                                   float* __restrict__ s2) {
    const int w = threadIdx.x >> 6, l = threadIdx.x & 63;
    const int row = blockIdx.x * 4 + w;
    const float* r = mk + (size_t)row * DDIM;
    float sum = 0.f, sq = 0.f;
#pragma unroll
    for (int i = 0; i < 4; ++i) {
        float4 v = *(const float4*)(r + i * 256 + l * 4);
        sum += v.x + v.y + v.z + v.w;
        sq  += v.x * v.x + v.y * v.y + v.z * v.z + v.w * v.w;
    }
#pragma unroll
    for (int off = 32; off; off >>= 1) {
        sum += __shfl_down(sum, off);
        sq  += __shfl_down(sq, off);
    }
    if (l == 0) {
        float val = sum / sqrtf(sq);
        s[row]  = val;
        s2[row] = -val;
    }
}

// ---------------------------------------------------------------------------
// 2) top-32 (value desc, tie -> lower index) of a 32768-float array.
//    block 0: s (qm>0 list), block 1: s2 (qm<0 list). 1024 threads, each owns
//    a contiguous 32-element segment with a taken-bitmask; per iteration a
//    wave-0 reduction picks the global argmax, only the winner rescans.
__global__ __launch_bounds__(1024) void topk_kernel(const float* __restrict__ sarr,
                                                    int* __restrict__ idx_out) {
    const float* s = sarr + blockIdx.x * MKEYS;
    int* out = idx_out + blockIdx.x * KSEL;
    const int t = threadIdx.x;
    const int base = t * 32;
    unsigned taken = 0u;

    float bv = -INFINITY; int bi = 0x7fffffff;
    for (int j = 0; j < 32; ++j) {
        float v = s[base + j];
        if (v > bv) { bv = v; bi = base + j; }
    }

    __shared__ float hv[1024];
    __shared__ int   hi[1024];
    __shared__ int   win_s;
    hv[t] = bv; hi[t] = bi;
    __syncthreads();

    for (int iter = 0; iter < KSEL; ++iter) {
        if (t < 64) {
            float rv = hv[t]; int ri = hi[t];
            for (int q = t + 64; q < 1024; q += 64) {
                float cv = hv[q]; int ci = hi[q];
                if (cv > rv || (cv == rv && ci < ri)) { rv = cv; ri = ci; }
            }
#pragma unroll
            for (int off = 32; off; off >>= 1) {
                float cv = __shfl_down(rv, off);
                int   ci = __shfl_down(ri, off);
                if (cv > rv || (cv == rv && ci < ri)) { rv = cv; ri = ci; }
            }
            if (t == 0) { win_s = ri; out[iter] = ri; }
        }
        __syncthreads();
        const int win = win_s;
        if ((win >> 5) == t) {       // my segment: mark + rescan
            taken |= 1u << (win & 31);
            bv = -INFINITY; bi = 0x7fffffff;
            for (int j = 0; j < 32; ++j) {
                if (taken & (1u << j)) continue;
                float v = s[base + j];
                if (v > bv) { bv = v; bi = base + j; }
            }
            hv[t] = bv; hi[t] = bi;
        }
        __syncthreads();
    }
}

// ---------------------------------------------------------------------------
// 3) generic fp32 tiled GEMM, C[M,N] = A[M,K] * B[N,K]^T  (both row-major).
//    BM=BN=64, BK=16, 256 threads, 4x4 acc per thread. Optional row gather
//    on A (for the 64 selected memory rows). All dims divide evenly here.
__global__ __launch_bounds__(256) void gemm_nt(const float* __restrict__ A,
                                               const float* __restrict__ B,
                                               float* __restrict__ C,
                                               int N, int Kdim,
                                               const int* __restrict__ gidx) {
    __shared__ float As[16][68];   // [k][m], pad 68 -> 16B-aligned float4 rows
    __shared__ float Bs[16][68];   // [k][n]
    const int tid = threadIdx.x;
    const int tx = tid & 15, ty = tid >> 4;
    const int m0 = blockIdx.y * 64, n0 = blockIdx.x * 64;
    const int lrow = tid >> 2;
    const int lk = (tid & 3) * 4;
    const int arow = gidx ? gidx[m0 + lrow] : (m0 + lrow);
    const float* aptr = A + (size_t)arow * Kdim + lk;
    const float* bptr = B + (size_t)(n0 + lrow) * Kdim + lk;

    float acc[4][4] = {};
    for (int k0 = 0; k0 < Kdim; k0 += 16) {
        float4 av = *(const float4*)(aptr + k0);
        float4 bv = *(const float4*)(bptr + k0);
        As[lk + 0][lrow] = av.x; As[lk + 1][lrow] = av.y;
        As[lk + 2][lrow] = av.z; As[lk + 3][lrow] = av.w;
        Bs[lk + 0][lrow] = bv.x; Bs[lk + 1][lrow] = bv.y;
        Bs[lk + 2][lrow] = bv.z; Bs[lk + 3][lrow] = bv.w;
        __syncthreads();
#pragma unroll
        for (int kk = 0; kk < 16; ++kk) {
            float a[4], b[4];
#pragma unroll
            for (int i = 0; i < 4; ++i) a[i] = As[kk][ty * 4 + i];
#pragma unroll
            for (int j = 0; j < 4; ++j) b[j] = Bs[kk][tx * 4 + j];
#pragma unroll
            for (int i = 0; i < 4; ++i)
#pragma unroll
                for (int j = 0; j < 4; ++j) acc[i][j] += a[i] * b[j];
        }
        __syncthreads();
    }
    float* cp = C + (size_t)(m0 + ty * 4) * N + n0 + tx * 4;
#pragma unroll
    for (int i = 0; i < 4; ++i) {
        float4 o = make_float4(acc[i][0], acc[i][1], acc[i][2], acc[i][3]);
        *(float4*)(cp + (size_t)i * N) = o;
    }
}

// ---------------------------------------------------------------------------
// 4) qm[row] = mean of q_full row (fp32 — protects the selection sign)
__global__ __launch_bounds__(256) void qm_kernel(const float* __restrict__ q_full,
                                                 float* __restrict__ qm) {
    const int w = threadIdx.x >> 6, l = threadIdx.x & 63;
    const int row = blockIdx.x * 4 + w;
    const float* r = q_full + (size_t)row * DDIM;
    float s = 0.f;
#pragma unroll
    for (int i = 0; i < 4; ++i) {
        float4 v = *(const float4*)(r + i * 256 + l * 4);
        s += v.x + v.y + v.z + v.w;
    }
#pragma unroll
    for (int off = 32; off; off >>= 1) s += __shfl_down(s, off);
    if (l == 0) qm[row] = s * (1.f / 1024.f);
}

// ---------------------------------------------------------------------------
// 5) attention: one block per token. scores -> softmax -> ctx; also writes
//    avg_attn and sel_idx (as float) straight into d_out.
__global__ __launch_bounds__(256) void attention_kernel(const float* __restrict__ q_full,
                                                        const float* __restrict__ qm,
                                                        const float* __restrict__ kp,
                                                        const float* __restrict__ vp,
                                                        const int* __restrict__ idx_list,
                                                        float* __restrict__ ctx,
                                                        float* __restrict__ out) {
    const int bn = blockIdx.x;
    const int t = threadIdx.x;
    __shared__ float qs[DDIM];
    __shared__ float sc[NHEAD][KSEL + 1];
    __shared__ int selbase_s;

    *(float4*)(qs + t * 4) = *(const float4*)(q_full + (size_t)bn * DDIM + t * 4);
    if (t == 0) selbase_s = (qm[bn] > 0.0f) ? 0 : KSEL;
    __syncthreads();
    const int selbase = selbase_s;

    // scores: 512 (h,k) pairs, 2 per thread; dot over hd=64
#pragma unroll
    for (int p = 0; p < 2; ++p) {
        const int pair = t + p * 256;
        const int h = pair >> 5, k = pair & 31;
        const float* kr = kp + (size_t)(selbase + k) * DDIM + h * HDIM;
        const float* qr = qs + h * HDIM;
        float acc = 0.f;
#pragma unroll
        for (int i = 0; i < 16; ++i) {
            float4 kv = *(const float4*)(kr + i * 4);
            acc += qr[i * 4 + 0] * kv.x + qr[i * 4 + 1] * kv.y +
                   qr[i * 4 + 2] * kv.z + qr[i * 4 + 3] * kv.w;
        }
        sc[h][k] = acc * 0.125f;   // / (sqrt(64) * T)
    }
    __syncthreads();

    if (t < NHEAD) {   // softmax over K per head
        float m = -INFINITY;
        for (int k = 0; k < KSEL; ++k) m = fmaxf(m, sc[t][k]);
        float ssum = 0.f;
        for (int k = 0; k < KSEL; ++k) { float e = __expf(sc[t][k] - m); sc[t][k] = e; ssum += e; }
        float inv = 1.f / ssum;
        for (int k = 0; k < KSEL; ++k) sc[t][k] *= inv;
    }
    __syncthreads();

    // ctx[o] = sum_k attn[h(o)][k] * vp[sel+k][o]  (coalesced over t)
#pragma unroll
    for (int c = 0; c < 4; ++c) {
        const int o = c * 256 + t;
        const int h = o >> 6;
        float acc = 0.f;
        for (int k = 0; k < KSEL; ++k)
            acc += sc[h][k] * vp[(size_t)(selbase + k) * DDIM + o];
        ctx[(size_t)bn * DDIM + o] = acc;
    }

    if (t < KSEL) {
        float a = 0.f;
#pragma unroll
        for (int h = 0; h < NHEAD; ++h) a += sc[h][t];
        out[OUT_AVG + bn * KSEL + t] = a * (1.f / 16.f);
        out[OUT_IDX + bn * KSEL + t] = (float)idx_list[selbase + t];
    }
}

// ---------------------------------------------------------------------------
// 6) LayerNorm row kernel: x = raw + bo; out = (x-mu)/sqrt(var+eps)*gamma+beta
__global__ __launch_bounds__(256) void ln_kernel(const float* __restrict__ raw,
                                                 const float* __restrict__ bo,
                                                 const float* __restrict__ gamma,
                                                 const float* __restrict__ beta,
                                                 float* __restrict__ out) {
    const int row = blockIdx.x;
    const int t = threadIdx.x;
    float4 v = *(const float4*)(raw + (size_t)row * DDIM + t * 4);
    float4 b = *(const float4*)(bo + t * 4);
    v.x += b.x; v.y += b.y; v.z += b.z; v.w += b.w;
    float s  = v.x + v.y + v.z + v.w;
    float ss = v.x * v.x + v.y * v.y + v.z * v.z + v.w * v.w;
#pragma unroll
    for (int off = 32; off; off >>= 1) {
        s  += __shfl_down(s, off);
        ss += __shfl_down(ss, off);
    }
    __shared__ float rs[4], rss[4];
    const int w = t >> 6, l = t & 63;
    if (l == 0) { rs[w] = s; rss[w] = ss; }
    __syncthreads();
    if (t == 0) {
        rs[0]  = rs[0] + rs[1] + rs[2] + rs[3];
        rss[0] = rss[0] + rss[1] + rss[2] + rss[3];
    }
    __syncthreads();
    const float mu  = rs[0] * (1.f / 1024.f);
    const float var = rss[0] * (1.f / 1024.f) - mu * mu;
    const float rstd = rsqrtf(var + 1e-5f);
    float4 g  = *(const float4*)(gamma + t * 4);
    float4 be = *(const float4*)(beta + t * 4);
    float4 o;
    o.x = (v.x - mu) * rstd * g.x + be.x;
    o.y = (v.y - mu) * rstd * g.y + be.y;
    o.z = (v.z - mu) * rstd * g.z + be.z;
    o.w = (v.w - mu) * rstd * g.w + be.w;
    *(float4*)(out + (size_t)row * DDIM + t * 4) = o;
}

// ---------------------------------------------------------------------------
extern "C" void kernel_launch(void* const* d_in, const int* in_sizes, int n_in,
                              void* d_out, int out_size, void* d_ws, size_t ws_size,
                              hipStream_t stream) {
    const float* x     = (const float*)d_in[0];
    const float* mk    = (const float*)d_in[1];
    const float* mv    = (const float*)d_in[2];
    const float* Wq    = (const float*)d_in[3];
    const float* Wk    = (const float*)d_in[4];
    const float* Wv    = (const float*)d_in[5];
    const float* Wo    = (const float*)d_in[6];
    const float* bo    = (const float*)d_in[7];
    const float* gamma = (const float*)d_in[8];
    const float* beta  = (const float*)d_in[9];

    float* ws  = (float*)d_ws;
    float* out = (float*)d_out;

    float* q_full = ws + WS_QFULL;
    float* ctx    = ws + WS_CTX;
    float* sarr   = ws + WS_S;      // s followed by s2 (contiguous)
    float* qm     = ws + WS_QM;
    float* kp     = ws + WS_KP;
    float* vp     = ws + WS_VP;
    int*   idx    = (int*)(ws + WS_IDX);
    float* raw    = ws + WS_RAW;    // aliases q_full (dead after attention)

    hipLaunchKernelGGL(reduce_keys, dim3(MKEYS / 4), dim3(256), 0, stream, mk, sarr, sarr + MKEYS);
    hipLaunchKernelGGL(gemm_nt, dim3(16, 32), dim3(256), 0, stream, x, Wq, q_full, DDIM, DDIM, (const int*)nullptr);
    hipLaunchKernelGGL(qm_kernel, dim3(BTOK / 4), dim3(256), 0, stream, q_full, qm);
    hipLaunchKernelGGL(topk_kernel, dim3(2), dim3(1024), 0, stream, sarr, idx);
    hipLaunchKernelGGL(gemm_nt, dim3(16, 1), dim3(256), 0, stream, mk, Wk, kp, DDIM, DDIM, idx);
    hipLaunchKernelGGL(gemm_nt, dim3(16, 1), dim3(256), 0, stream, mv, Wv, vp, DDIM, DDIM, idx);
    hipLaunchKernelGGL(attention_kernel, dim3(BTOK), dim3(256), 0, stream, q_full, qm, kp, vp, idx, ctx, out);
    hipLaunchKernelGGL(gemm_nt, dim3(16, 32), dim3(256), 0, stream, ctx, Wo, raw, DDIM, DDIM, (const int*)nullptr);
    hipLaunchKernelGGL(ln_kernel, dim3(BTOK), dim3(256), 0, stream, raw, bo, gamma, beta, out);
}

// Round 2
// 524.223 us; speedup vs baseline: 1.3683x; 1.3683x over previous
//
#include <hip/hip_runtime.h>

// Problem constants (B=4, N=512, M=32768, D=1024, H=16, hd=64, K=32)
#define BTOK   2048
#define DDIM   1024
#define MKEYS  32768
#define NHEAD  16
#define HDIM   64
#define KSEL   32

// workspace layout (float offsets)
#define WS_QFULL 0
#define WS_CTX   (BTOK * DDIM)                 // 2097152
#define WS_S     (WS_CTX + BTOK * DDIM)        // 4194304
#define WS_S2    (WS_S + MKEYS)                // 4227072
#define WS_QM    (WS_S2 + MKEYS)               // 4259840
#define WS_KP    (WS_QM + BTOK)                // 4261888
#define WS_VP    (WS_KP + 64 * DDIM)           // 4327424
#define WS_IDX   (WS_VP + 64 * DDIM)           // 4392960 (64 ints)
#define WS_RAW   WS_QFULL                      // out_raw aliases q_full (dead after attention)

// d_out layout (float offsets)
#define OUT_AVG  (BTOK * DDIM)                 // 2097152
#define OUT_IDX  (OUT_AVG + BTOK * KSEL)       // 2162688

// ---------------------------------------------------------------------------
// 1) per-row sum and norm of memory_keys -> s[m] = sum/norm, s2[m] = -s[m]
__global__ __launch_bounds__(256) void reduce_keys(const float* __restrict__ mk,
                                                   float* __restrict__ s,
                                                   float* __restrict__ s2) {
    const int w = threadIdx.x >> 6, l = threadIdx.x & 63;
    const int row = blockIdx.x * 4 + w;
    const float* r = mk + (size_t)row * DDIM;
    float sum = 0.f, sq = 0.f;
#pragma unroll
    for (int i = 0; i < 4; ++i) {
        float4 v = *(const float4*)(r + i * 256 + l * 4);
        sum += v.x + v.y + v.z + v.w;
        sq  += v.x * v.x + v.y * v.y + v.z * v.z + v.w * v.w;
    }
#pragma unroll
    for (int off = 32; off; off >>= 1) {
        sum += __shfl_down(sum, off);
        sq  += __shfl_down(sq, off);
    }
    if (l == 0) {
        float val = sum / sqrtf(sq);
        s[row]  = val;
        s2[row] = -val;
    }
}

// ---------------------------------------------------------------------------
// 2) radix-select top-32 (value desc, tie -> lower index) of 32768 floats.
//    block 0: s, block 1: s2. Histogram of top-12 bits of the order key,
//    cutoff-bin scan, candidate gather, exact wave-level selection.
__global__ __launch_bounds__(1024) void topk_radix(const float* __restrict__ sarr,
                                                   int* __restrict__ idx_out) {
    const float* s = sarr + blockIdx.x * MKEYS;
    int* out = idx_out + blockIdx.x * KSEL;
    const int t = threadIdx.x;

    __shared__ int   hist[4096];
    __shared__ int   csum[64];
    __shared__ int   binB_s;
    __shared__ int   ccnt;
    __shared__ float cval[1024];
    __shared__ int   cidx[1024];

    for (int i = t; i < 4096; i += 1024) hist[i] = 0;
    if (t == 0) ccnt = 0;
    __syncthreads();

    // pass 1: coalesced histogram of order-transformed keys
    for (int j = 0; j < 32; ++j) {
        unsigned u = __float_as_uint(s[t + j * 1024]);
        unsigned k = u ^ (unsigned)(((int)u >> 31) | (int)0x80000000);
        atomicAdd(&hist[k >> 20], 1);
    }
    __syncthreads();

    // hierarchical cutoff-bin search
    if (t < 64) {
        int acc = 0;
        for (int j = 0; j < 64; ++j) acc += hist[t * 64 + j];
        csum[t] = acc;
    }
    __syncthreads();
    if (t == 0) {
        int acc = 0, cb = 63;
        for (; cb > 0; --cb) {
            if (acc + csum[cb] >= KSEL) break;
            acc += csum[cb];
        }
        int b = cb * 64 + 63;
        for (; b > cb * 64; --b) {
            if (acc + hist[b] >= KSEL) break;
            acc += hist[b];
        }
        binB_s = b;
    }
    __syncthreads();
    const unsigned binB = (unsigned)binB_s;

    // pass 2: gather candidates (bin >= cutoff bin); expected ~40-100
    for (int j = 0; j < 32; ++j) {
        const int ii = t + j * 1024;
        float v = s[ii];
        unsigned u = __float_as_uint(v);
        unsigned k = u ^ (unsigned)(((int)u >> 31) | (int)0x80000000);
        if ((k >> 20) >= binB) {
            int p = atomicAdd(&ccnt, 1);
            if (p < 1024) { cval[p] = v; cidx[p] = ii; }
        }
    }
    __syncthreads();

    // exact top-32 over candidates, single wave (lockstep, no barriers)
    const int n = min(ccnt, 1024);
    if (t < 64) {
        for (int iter = 0; iter < KSEL; ++iter) {
            float bv = -INFINITY; int bi = 0x7fffffff; int bs = -1;
            for (int j = t; j < n; j += 64) {
                float v = cval[j]; int ii = cidx[j];
                if (v > bv || (v == bv && ii < bi)) { bv = v; bi = ii; bs = j; }
            }
#pragma unroll
            for (int off = 32; off; off >>= 1) {
                float ov = __shfl_down(bv, off);
                int   oi = __shfl_down(bi, off);
                int   os = __shfl_down(bs, off);
                if (ov > bv || (ov == bv && oi < bi)) { bv = ov; bi = oi; bs = os; }
            }
            bs = __shfl(bs, 0);
            if (t == 0) {
                out[iter] = bi;
                cval[bs] = -INFINITY;   // mark taken; same-wave ds order is safe
            }
        }
    }
}

// ---------------------------------------------------------------------------
// 3) fp32 tiled GEMM body, C[M,N] = A[M,K] * B[N,K]^T, double-buffered LDS
//    with one-tile global prefetch. BM=BN=64, BK=16, 256 threads, 4x4 acc.
__device__ __forceinline__ void gemm_body(const float* __restrict__ A,
                                          const float* __restrict__ B,
                                          float* __restrict__ C,
                                          int N, int Kdim,
                                          const int* __restrict__ gidx,
                                          int m0, int n0) {
    __shared__ float As[2][16][68];
    __shared__ float Bs[2][16][68];
    const int tid = threadIdx.x;
    const int tx = tid & 15, ty = tid >> 4;
    const int lrow = tid >> 2;
    const int lk = (tid & 3) * 4;
    const int arow = gidx ? gidx[m0 + lrow] : (m0 + lrow);
    const float* aptr = A + (size_t)arow * Kdim + lk;
    const float* bptr = B + (size_t)(n0 + lrow) * Kdim + lk;

    float4 av = *(const float4*)(aptr);
    float4 bv = *(const float4*)(bptr);
    As[0][lk + 0][lrow] = av.x; As[0][lk + 1][lrow] = av.y;
    As[0][lk + 2][lrow] = av.z; As[0][lk + 3][lrow] = av.w;
    Bs[0][lk + 0][lrow] = bv.x; Bs[0][lk + 1][lrow] = bv.y;
    Bs[0][lk + 2][lrow] = bv.z; Bs[0][lk + 3][lrow] = bv.w;
    __syncthreads();

    float acc[4][4] = {};
    const int nt = Kdim >> 4;
    int cb = 0;
    for (int tk = 0; tk < nt; ++tk) {
        float4 av2, bv2;
        const bool more = (tk + 1 < nt);
        if (more) {   // prefetch next tile while computing current
            av2 = *(const float4*)(aptr + (tk + 1) * 16);
            bv2 = *(const float4*)(bptr + (tk + 1) * 16);
        }
#pragma unroll
        for (int kk = 0; kk < 16; ++kk) {
            float a[4], b[4];
#pragma unroll
            for (int i = 0; i < 4; ++i) a[i] = As[cb][kk][ty * 4 + i];
#pragma unroll
            for (int j = 0; j < 4; ++j) b[j] = Bs[cb][kk][tx * 4 + j];
#pragma unroll
            for (int i = 0; i < 4; ++i)
#pragma unroll
                for (int j = 0; j < 4; ++j) acc[i][j] += a[i] * b[j];
        }
        if (more) {
            const int nb = cb ^ 1;
            As[nb][lk + 0][lrow] = av2.x; As[nb][lk + 1][lrow] = av2.y;
            As[nb][lk + 2][lrow] = av2.z; As[nb][lk + 3][lrow] = av2.w;
            Bs[nb][lk + 0][lrow] = bv2.x; Bs[nb][lk + 1][lrow] = bv2.y;
            Bs[nb][lk + 2][lrow] = bv2.z; Bs[nb][lk + 3][lrow] = bv2.w;
        }
        __syncthreads();
        cb ^= 1;
    }

    float* cp = C + (size_t)(m0 + ty * 4) * N + n0 + tx * 4;
#pragma unroll
    for (int i = 0; i < 4; ++i) {
        float4 o = make_float4(acc[i][0], acc[i][1], acc[i][2], acc[i][3]);
        *(float4*)(cp + (size_t)i * N) = o;
    }
}

__global__ __launch_bounds__(256) void gemm_nt(const float* __restrict__ A,
                                               const float* __restrict__ B,
                                               float* __restrict__ C,
                                               int N, int Kdim,
                                               const int* __restrict__ gidx) {
    gemm_body(A, B, C, N, Kdim, gidx, blockIdx.y * 64, blockIdx.x * 64);
}

// merged K/V projection of the 64 selected rows: blockIdx.y picks (mk,Wk,kp)
// vs (mv,Wv,vp); one dispatch instead of two serialized 16-block launches.
__global__ __launch_bounds__(256) void gemm_kv(const float* __restrict__ mk,
                                               const float* __restrict__ mv,
                                               const float* __restrict__ Wk,
                                               const float* __restrict__ Wv,
                                               float* __restrict__ kp,
                                               float* __restrict__ vp,
                                               const int* __restrict__ gidx) {
    const int which = blockIdx.y;
    const float* A = which ? mv : mk;
    const float* B = which ? Wv : Wk;
    float*       C = which ? vp : kp;
    gemm_body(A, B, C, DDIM, DDIM, gidx, 0, blockIdx.x * 64);
}

// ---------------------------------------------------------------------------
// 4) qm[row] = mean of q_full row (fp32 — protects the selection sign)
__global__ __launch_bounds__(256) void qm_kernel(const float* __restrict__ q_full,
                                                 float* __restrict__ qm) {
    const int w = threadIdx.x >> 6, l = threadIdx.x & 63;
    const int row = blockIdx.x * 4 + w;
    const float* r = q_full + (size_t)row * DDIM;
    float s = 0.f;
#pragma unroll
    for (int i = 0; i < 4; ++i) {
        float4 v = *(const float4*)(r + i * 256 + l * 4);
        s += v.x + v.y + v.z + v.w;
    }
#pragma unroll
    for (int off = 32; off; off >>= 1) s += __shfl_down(s, off);
    if (l == 0) qm[row] = s * (1.f / 1024.f);
}

// ---------------------------------------------------------------------------
// 5) attention: one block per token. scores -> softmax -> ctx; also writes
//    avg_attn and sel_idx (as float) straight into d_out.
__global__ __launch_bounds__(256) void attention_kernel(const float* __restrict__ q_full,
                                                        const float* __restrict__ qm,
                                                        const float* __restrict__ kp,
                                                        const float* __restrict__ vp,
                                                        const int* __restrict__ idx_list,
                                                        float* __restrict__ ctx,
                                                        float* __restrict__ out) {
    const int bn = blockIdx.x;
    const int t = threadIdx.x;
    __shared__ float qs[DDIM];
    __shared__ float sc[NHEAD][KSEL + 1];
    __shared__ int selbase_s;

    *(float4*)(qs + t * 4) = *(const float4*)(q_full + (size_t)bn * DDIM + t * 4);
    if (t == 0) selbase_s = (qm[bn] > 0.0f) ? 0 : KSEL;
    __syncthreads();
    const int selbase = selbase_s;

#pragma unroll
    for (int p = 0; p < 2; ++p) {
        const int pair = t + p * 256;
        const int h = pair >> 5, k = pair & 31;
        const float* kr = kp + (size_t)(selbase + k) * DDIM + h * HDIM;
        const float* qr = qs + h * HDIM;
        float acc = 0.f;
#pragma unroll
        for (int i = 0; i < 16; ++i) {
            float4 kv = *(const float4*)(kr + i * 4);
            acc += qr[i * 4 + 0] * kv.x + qr[i * 4 + 1] * kv.y +
                   qr[i * 4 + 2] * kv.z + qr[i * 4 + 3] * kv.w;
        }
        sc[h][k] = acc * 0.125f;   // / (sqrt(64) * T)
    }
    __syncthreads();

    if (t < NHEAD) {
        float m = -INFINITY;
        for (int k = 0; k < KSEL; ++k) m = fmaxf(m, sc[t][k]);
        float ssum = 0.f;
        for (int k = 0; k < KSEL; ++k) { float e = __expf(sc[t][k] - m); sc[t][k] = e; ssum += e; }
        float inv = 1.f / ssum;
        for (int k = 0; k < KSEL; ++k) sc[t][k] *= inv;
    }
    __syncthreads();

#pragma unroll
    for (int c = 0; c < 4; ++c) {
        const int o = c * 256 + t;
        const int h = o >> 6;
        float acc = 0.f;
        for (int k = 0; k < KSEL; ++k)
            acc += sc[h][k] * vp[(size_t)(selbase + k) * DDIM + o];
        ctx[(size_t)bn * DDIM + o] = acc;
    }

    if (t < KSEL) {
        float a = 0.f;
#pragma unroll
        for (int h = 0; h < NHEAD; ++h) a += sc[h][t];
        out[OUT_AVG + bn * KSEL + t] = a * (1.f / 16.f);
        out[OUT_IDX + bn * KSEL + t] = (float)idx_list[selbase + t];
    }
}

// ---------------------------------------------------------------------------
// 6) LayerNorm row kernel
__global__ __launch_bounds__(256) void ln_kernel(const float* __restrict__ raw,
                                                 const float* __restrict__ bo,
                                                 const float* __restrict__ gamma,
                                                 const float* __restrict__ beta,
                                                 float* __restrict__ out) {
    const int row = blockIdx.x;
    const int t = threadIdx.x;
    float4 v = *(const float4*)(raw + (size_t)row * DDIM + t * 4);
    float4 b = *(const float4*)(bo + t * 4);
    v.x += b.x; v.y += b.y; v.z += b.z; v.w += b.w;
    float s  = v.x + v.y + v.z + v.w;
    float ss = v.x * v.x + v.y * v.y + v.z * v.z + v.w * v.w;
#pragma unroll
    for (int off = 32; off; off >>= 1) {
        s  += __shfl_down(s, off);
        ss += __shfl_down(ss, off);
    }
    __shared__ float rs[4], rss[4];
    const int w = t >> 6, l = t & 63;
    if (l == 0) { rs[w] = s; rss[w] = ss; }
    __syncthreads();
    if (t == 0) {
        rs[0]  = rs[0] + rs[1] + rs[2] + rs[3];
        rss[0] = rss[0] + rss[1] + rss[2] + rss[3];
    }
    __syncthreads();
    const float mu  = rs[0] * (1.f / 1024.f);
    const float var = rss[0] * (1.f / 1024.f) - mu * mu;
    const float rstd = rsqrtf(var + 1e-5f);
    float4 g  = *(const float4*)(gamma + t * 4);
    float4 be = *(const float4*)(beta + t * 4);
    float4 o;
    o.x = (v.x - mu) * rstd * g.x + be.x;
    o.y = (v.y - mu) * rstd * g.y + be.y;
    o.z = (v.z - mu) * rstd * g.z + be.z;
    o.w = (v.w - mu) * rstd * g.w + be.w;
    *(float4*)(out + (size_t)row * DDIM + t * 4) = o;
}

// ---------------------------------------------------------------------------
extern "C" void kernel_launch(void* const* d_in, const int* in_sizes, int n_in,
                              void* d_out, int out_size, void* d_ws, size_t ws_size,
                              hipStream_t stream) {
    const float* x     = (const float*)d_in[0];
    const float* mk    = (const float*)d_in[1];
    const float* mv    = (const float*)d_in[2];
    const float* Wq    = (const float*)d_in[3];
    const float* Wk    = (const float*)d_in[4];
    const float* Wv    = (const float*)d_in[5];
    const float* Wo    = (const float*)d_in[6];
    const float* bo    = (const float*)d_in[7];
    const float* gamma = (const float*)d_in[8];
    const float* beta  = (const float*)d_in[9];

    float* ws  = (float*)d_ws;
    float* out = (float*)d_out;

    float* q_full = ws + WS_QFULL;
    float* ctx    = ws + WS_CTX;
    float* sarr   = ws + WS_S;      // s followed by s2 (contiguous)
    float* qm     = ws + WS_QM;
    float* kp     = ws + WS_KP;
    float* vp     = ws + WS_VP;
    int*   idx    = (int*)(ws + WS_IDX);
    float* raw    = ws + WS_RAW;    // aliases q_full (dead after attention)

    hipLaunchKernelGGL(reduce_keys, dim3(MKEYS / 4), dim3(256), 0, stream, mk, sarr, sarr + MKEYS);
    hipLaunchKernelGGL(gemm_nt, dim3(16, 32), dim3(256), 0, stream, x, Wq, q_full, DDIM, DDIM, (const int*)nullptr);
    hipLaunchKernelGGL(qm_kernel, dim3(BTOK / 4), dim3(256), 0, stream, q_full, qm);
    hipLaunchKernelGGL(topk_radix, dim3(2), dim3(1024), 0, stream, sarr, idx);
    hipLaunchKernelGGL(gemm_kv, dim3(16, 2), dim3(256), 0, stream, mk, mv, Wk, Wv, kp, vp, idx);
    hipLaunchKernelGGL(attention_kernel, dim3(BTOK), dim3(256), 0, stream, q_full, qm, kp, vp, idx, ctx, out);
    hipLaunchKernelGGL(gemm_nt, dim3(16, 32), dim3(256), 0, stream, ctx, Wo, raw, DDIM, DDIM, (const int*)nullptr);
    hipLaunchKernelGGL(ln_kernel, dim3(BTOK), dim3(256), 0, stream, raw, bo, gamma, beta, out);
}